// Round 1
// baseline (233.994 us; speedup 1.0000x reference)
//
#include <hip/hip_runtime.h>
#include <cfloat>
#include <cstdint>

#define K 8
#define NT 256
#define NW (NT / 64)

__global__ __launch_bounds__(NT) void topk8_kernel(const float* __restrict__ x,
                                                   float* __restrict__ out,
                                                   int ncols, int nrows) {
    const int row = blockIdx.x;
    const int tid = threadIdx.x;
    const float* __restrict__ rowp = x + (size_t)row * (size_t)ncols;

    // Per-thread top-8, sorted descending by value; ties hold the smaller index
    // higher. All accesses use compile-time indices -> stays in VGPRs.
    float v[K];
    int   id[K];
#pragma unroll
    for (int i = 0; i < K; ++i) { v[i] = -FLT_MAX; id[i] = 0x7fffffff; }

    auto insert = [&](float val, int idx) {
        if (val > v[K - 1]) {
            v[K - 1] = val; id[K - 1] = idx;
#pragma unroll
            for (int p = K - 1; p > 0; --p) {
                // New element bubbles up only past strictly-smaller values, so
                // equal values keep ascending-index order (stable like lax.top_k:
                // within a thread, indices are scanned in increasing order).
                if (v[p] > v[p - 1]) {
                    float tv = v[p]; v[p] = v[p - 1]; v[p - 1] = tv;
                    int   ti = id[p]; id[p] = id[p - 1]; id[p - 1] = ti;
                }
            }
        }
    };

    // Alignment prologue: row base may be misaligned for float4 (stride 50257).
    const int mis  = (int)(((uintptr_t)rowp >> 2) & 3);   // element offset mod 4
    int head = (4 - mis) & 3;
    if (head > ncols) head = ncols;
    if (tid < head) insert(rowp[tid], tid);

    const int nvec = (ncols - head) >> 2;
    const float4* __restrict__ vp = (const float4*)(rowp + head);
    for (int j = tid; j < nvec; j += NT) {
        float4 f = vp[j];
        const int b = head + 4 * j;
        insert(f.x, b);
        insert(f.y, b + 1);
        insert(f.z, b + 2);
        insert(f.w, b + 3);
    }

    const int tb = head + 4 * nvec;
    for (int c = tb + tid; c < ncols; c += NT) insert(rowp[c], c);

    // Block-wide top-8 extraction: 8 rounds of argmax over each thread's head.
    __shared__ float sv[NW];
    __shared__ int   si[NW];
    __shared__ int   st[NW];
    __shared__ float rv[K];
    __shared__ int   ri[K];

    const int lane = tid & 63;
    const int wave = tid >> 6;

    for (int r = 0; r < K; ++r) {
        float bv = v[0];
        int   bi = id[0];
        int   bt = tid;
#pragma unroll
        for (int off = 32; off >= 1; off >>= 1) {
            float ov = __shfl_xor(bv, off);
            int   oi = __shfl_xor(bi, off);
            int   ot = __shfl_xor(bt, off);
            if (ov > bv || (ov == bv && oi < bi)) { bv = ov; bi = oi; bt = ot; }
        }
        if (lane == 0) { sv[wave] = bv; si[wave] = bi; st[wave] = bt; }
        __syncthreads();

        float wv = sv[0]; int wi = si[0]; int wt = st[0];
#pragma unroll
        for (int w = 1; w < NW; ++w) {
            if (sv[w] > wv || (sv[w] == wv && si[w] < wi)) {
                wv = sv[w]; wi = si[w]; wt = st[w];
            }
        }

        if (tid == wt) {
            // Pop my head: shift register list up (compile-time indices only).
#pragma unroll
            for (int p = 0; p < K - 1; ++p) { v[p] = v[p + 1]; id[p] = id[p + 1]; }
            v[K - 1] = -FLT_MAX; id[K - 1] = 0x7fffffff;
        }
        if (tid == 0) { rv[r] = wv; ri[r] = wi; }
        __syncthreads();
    }

    // Flat output: [nrows*K values (f32)] then [nrows*K indices (as f32)].
    if (tid < K) {
        out[(size_t)row * K + tid]                      = rv[tid];
        out[(size_t)nrows * K + (size_t)row * K + tid]  = (float)ri[tid];
    }
}

extern "C" void kernel_launch(void* const* d_in, const int* in_sizes, int n_in,
                              void* d_out, int out_size, void* d_ws, size_t ws_size,
                              hipStream_t stream) {
    const float* x = (const float*)d_in[0];
    float* out = (float*)d_out;
    const int nrows = 4096;
    const int ncols = in_sizes[0] / nrows;   // 50257
    topk8_kernel<<<nrows, NT, 0, stream>>>(x, out, ncols, nrows);
}

// Round 2
// 163.114 us; speedup vs baseline: 1.4345x; 1.4345x over previous
//
#include <hip/hip_runtime.h>
#include <cfloat>
#include <cstdint>

#define K 8
#define NT 256
#define NW (NT / 64)
#define WARM 4
#define CH2 12

__global__ __launch_bounds__(NT) void topk8_kernel(const float* __restrict__ x,
                                                   float* __restrict__ out,
                                                   int ncols, int nrows) {
    const int row  = blockIdx.x;
    const int tid  = threadIdx.x;
    const int lane = tid & 63;
    const int wave = tid >> 6;
    const float* __restrict__ rowp = x + (size_t)row * (size_t)ncols;

    __shared__ float sw[NW * K];   // refresh scratch: per-wave top-8 values
    __shared__ float sv[NW];
    __shared__ int   si[NW];
    __shared__ int   st[NW];
    __shared__ float rv[K];
    __shared__ int   ri[K];

    // Per-thread top-8, sorted descending; compile-time indices only (VGPRs).
    float v[K];
    int   id[K];
#pragma unroll
    for (int i = 0; i < K; ++i) { v[i] = -FLT_MAX; id[i] = 0x7fffffff; }

    auto insert = [&](float val, int idx) {
        if (val > v[K - 1]) {
            v[K - 1] = val; id[K - 1] = idx;
#pragma unroll
            for (int p = K - 1; p > 0; --p) {
                if (v[p] > v[p - 1]) {
                    float tv = v[p]; v[p] = v[p - 1]; v[p - 1] = tv;
                    int   ti = id[p]; id[p] = id[p - 1]; id[p - 1] = ti;
                }
            }
        }
    };

    // Block-wide "8th largest of everything retained so far" — a provable
    // lower bound on the row's final 8th value, used as the streaming gate.
    auto refresh = [&](float Told) -> float {
        float t0 = v[0], t1 = v[1], t2 = v[2], t3 = v[3];
        float t4 = v[4], t5 = v[5], t6 = v[6], t7 = v[7];
#pragma unroll
        for (int r = 0; r < K; ++r) {
            float m = t0;
#pragma unroll
            for (int off = 32; off >= 1; off >>= 1)
                m = fmaxf(m, __shfl_xor(m, off));
            const bool pop = (t0 == m);   // ties pop together: T only shrinks -> still a valid lower bound
            t0 = pop ? t1 : t0;
            t1 = pop ? t2 : t1;
            t2 = pop ? t3 : t2;
            t3 = pop ? t4 : t3;
            t4 = pop ? t5 : t4;
            t5 = pop ? t6 : t5;
            t6 = pop ? t7 : t6;
            t7 = pop ? -FLT_MAX : t7;
            if (lane == 0) sw[wave * K + r] = m;
        }
        __syncthreads();
        // Block 8th of the 4 waves' top-8 lists: branchless med3 insertion.
        float g0 = -FLT_MAX, g1 = -FLT_MAX, g2 = -FLT_MAX, g3 = -FLT_MAX;
        float g4 = -FLT_MAX, g5 = -FLT_MAX, g6 = -FLT_MAX, g7 = -FLT_MAX;
#pragma unroll
        for (int i = 0; i < NW * K; ++i) {
            const float xx = sw[i];
            g7 = __builtin_amdgcn_fmed3f(g6, g7, xx);
            g6 = __builtin_amdgcn_fmed3f(g5, g6, xx);
            g5 = __builtin_amdgcn_fmed3f(g4, g5, xx);
            g4 = __builtin_amdgcn_fmed3f(g3, g4, xx);
            g3 = __builtin_amdgcn_fmed3f(g2, g3, xx);
            g2 = __builtin_amdgcn_fmed3f(g1, g2, xx);
            g1 = __builtin_amdgcn_fmed3f(g0, g1, xx);
            g0 = fmaxf(g0, xx);
        }
        __syncthreads();   // protect sw for the next refresh
        return fmaxf(Told, g7);
    };

    // Alignment prologue (row stride 50257 elements is not 16B-aligned).
    const int mis  = (int)(((uintptr_t)rowp >> 2) & 3);
    int head = (4 - mis) & 3;
    if (head > ncols) head = ncols;
    if (tid < head) insert(rowp[tid], tid);

    const int nvec4 = (ncols - head) >> 2;
    const float4* __restrict__ vp = (const float4*)(rowp + head);

    int j = tid;

    // Warmup: ungated (T not yet meaningful).
    for (int w = 0; w < WARM; ++w, j += NT) {
        if (j < nvec4) {
            float4 f = vp[j];
            const int b = head + 4 * j;
            insert(f.x, b); insert(f.y, b + 1); insert(f.z, b + 2); insert(f.w, b + 3);
        }
    }

    float T = refresh(-FLT_MAX);

    // Chunk 2: gated.
    for (int w = 0; w < CH2; ++w, j += NT) {
        if (j < nvec4) {
            float4 f = vp[j];
            const float m = fmaxf(fmaxf(f.x, f.y), fmaxf(f.z, f.w));
            if (m >= T) {
                const int b = head + 4 * j;
                if (f.x >= T) insert(f.x, b);
                if (f.y >= T) insert(f.y, b + 1);
                if (f.z >= T) insert(f.z, b + 2);
                if (f.w >= T) insert(f.w, b + 3);
            }
        }
    }

    T = refresh(T);

    // Chunk 3: gated, 2 float4s per iteration for more loads in flight.
    for (; j + NT < nvec4; j += 2 * NT) {
        float4 f0 = vp[j];
        float4 f1 = vp[j + NT];
        const float m0 = fmaxf(fmaxf(f0.x, f0.y), fmaxf(f0.z, f0.w));
        const float m1 = fmaxf(fmaxf(f1.x, f1.y), fmaxf(f1.z, f1.w));
        if (m0 >= T) {
            const int b = head + 4 * j;
            if (f0.x >= T) insert(f0.x, b);
            if (f0.y >= T) insert(f0.y, b + 1);
            if (f0.z >= T) insert(f0.z, b + 2);
            if (f0.w >= T) insert(f0.w, b + 3);
        }
        if (m1 >= T) {
            const int b = head + 4 * (j + NT);
            if (f1.x >= T) insert(f1.x, b);
            if (f1.y >= T) insert(f1.y, b + 1);
            if (f1.z >= T) insert(f1.z, b + 2);
            if (f1.w >= T) insert(f1.w, b + 3);
        }
    }
    for (; j < nvec4; j += NT) {
        float4 f = vp[j];
        const float m = fmaxf(fmaxf(f.x, f.y), fmaxf(f.z, f.w));
        if (m >= T) {
            const int b = head + 4 * j;
            if (f.x >= T) insert(f.x, b);
            if (f.y >= T) insert(f.y, b + 1);
            if (f.z >= T) insert(f.z, b + 2);
            if (f.w >= T) insert(f.w, b + 3);
        }
    }

    // Scalar tail.
    const int tb = head + 4 * nvec4;
    for (int c = tb + tid; c < ncols; c += NT) insert(rowp[c], c);

    // Final block-wide top-8 extraction (identical semantics to round 1).
    for (int r = 0; r < K; ++r) {
        float bv = v[0];
        int   bi = id[0];
        int   bt = tid;
#pragma unroll
        for (int off = 32; off >= 1; off >>= 1) {
            float ov = __shfl_xor(bv, off);
            int   oi = __shfl_xor(bi, off);
            int   ot = __shfl_xor(bt, off);
            if (ov > bv || (ov == bv && oi < bi)) { bv = ov; bi = oi; bt = ot; }
        }
        if (lane == 0) { sv[wave] = bv; si[wave] = bi; st[wave] = bt; }
        __syncthreads();

        float wv = sv[0]; int wi = si[0]; int wt = st[0];
#pragma unroll
        for (int w = 1; w < NW; ++w) {
            if (sv[w] > wv || (sv[w] == wv && si[w] < wi)) {
                wv = sv[w]; wi = si[w]; wt = st[w];
            }
        }

        if (tid == wt) {
#pragma unroll
            for (int p = 0; p < K - 1; ++p) { v[p] = v[p + 1]; id[p] = id[p + 1]; }
            v[K - 1] = -FLT_MAX; id[K - 1] = 0x7fffffff;
        }
        if (tid == 0) { rv[r] = wv; ri[r] = wi; }
        __syncthreads();
    }

    if (tid < K) {
        out[(size_t)row * K + tid]                     = rv[tid];
        out[(size_t)nrows * K + (size_t)row * K + tid] = (float)ri[tid];
    }
}

extern "C" void kernel_launch(void* const* d_in, const int* in_sizes, int n_in,
                              void* d_out, int out_size, void* d_ws, size_t ws_size,
                              hipStream_t stream) {
    const float* x = (const float*)d_in[0];
    float* out = (float*)d_out;
    const int nrows = 4096;
    const int ncols = in_sizes[0] / nrows;   // 50257
    topk8_kernel<<<nrows, NT, 0, stream>>>(x, out, ncols, nrows);
}

// Round 3
// 147.830 us; speedup vs baseline: 1.5829x; 1.1034x over previous
//
#include <hip/hip_runtime.h>
#include <cfloat>
#include <cstdint>

#define K 8
#define NT 256
#define NW (NT / 64)
#define WARM 4
#define CH2 16

typedef float f32x4 __attribute__((ext_vector_type(4)));

__global__ __launch_bounds__(NT) void topk8_kernel(const float* __restrict__ x,
                                                   float* __restrict__ out,
                                                   int ncols, int nrows) {
    const int row  = blockIdx.x;
    const int tid  = threadIdx.x;
    const int lane = tid & 63;
    const int wave = tid >> 6;
    const float* __restrict__ rowp = x + (size_t)row * (size_t)ncols;

    __shared__ float sw[NW * K];   // refresh scratch: per-wave top-8 values
    __shared__ float sv[NW];
    __shared__ int   si[NW];
    __shared__ int   st[NW];
    __shared__ float rv[K];
    __shared__ int   ri[K];

    // Per-thread top-8, sorted descending; compile-time indices only (VGPRs).
    float v[K];
    int   id[K];
#pragma unroll
    for (int i = 0; i < K; ++i) { v[i] = -FLT_MAX; id[i] = 0x7fffffff; }

    auto insert = [&](float val, int idx) {
        if (val > v[K - 1]) {
            v[K - 1] = val; id[K - 1] = idx;
#pragma unroll
            for (int p = K - 1; p > 0; --p) {
                if (v[p] > v[p - 1]) {
                    float tv = v[p]; v[p] = v[p - 1]; v[p - 1] = tv;
                    int   ti = id[p]; id[p] = id[p - 1]; id[p - 1] = ti;
                }
            }
        }
    };

    // Block-wide "8th largest of everything retained so far" — a provable
    // lower bound on the row's final 8th value (8th of subset <= 8th of
    // superset), used as the streaming gate. Ties popping together only
    // shrink the result -> still a valid lower bound.
    auto refresh = [&](float Told) -> float {
        float t0 = v[0], t1 = v[1], t2 = v[2], t3 = v[3];
        float t4 = v[4], t5 = v[5], t6 = v[6], t7 = v[7];
#pragma unroll
        for (int r = 0; r < K; ++r) {
            float m = t0;
#pragma unroll
            for (int off = 32; off >= 1; off >>= 1)
                m = fmaxf(m, __shfl_xor(m, off));
            const bool pop = (t0 == m);
            t0 = pop ? t1 : t0;
            t1 = pop ? t2 : t1;
            t2 = pop ? t3 : t2;
            t3 = pop ? t4 : t3;
            t4 = pop ? t5 : t4;
            t5 = pop ? t6 : t5;
            t6 = pop ? t7 : t6;
            t7 = pop ? -FLT_MAX : t7;
            if (lane == 0) sw[wave * K + r] = m;
        }
        __syncthreads();
        float g0 = -FLT_MAX, g1 = -FLT_MAX, g2 = -FLT_MAX, g3 = -FLT_MAX;
        float g4 = -FLT_MAX, g5 = -FLT_MAX, g6 = -FLT_MAX, g7 = -FLT_MAX;
#pragma unroll
        for (int i = 0; i < NW * K; ++i) {
            const float xx = sw[i];
            g7 = __builtin_amdgcn_fmed3f(g6, g7, xx);
            g6 = __builtin_amdgcn_fmed3f(g5, g6, xx);
            g5 = __builtin_amdgcn_fmed3f(g4, g5, xx);
            g4 = __builtin_amdgcn_fmed3f(g3, g4, xx);
            g3 = __builtin_amdgcn_fmed3f(g2, g3, xx);
            g2 = __builtin_amdgcn_fmed3f(g1, g2, xx);
            g1 = __builtin_amdgcn_fmed3f(g0, g1, xx);
            g0 = fmaxf(g0, xx);
        }
        __syncthreads();   // protect sw for the next refresh
        return fmaxf(Told, g7);
    };

    // Alignment prologue (row stride 50257 elements is not 16B-aligned).
    const int mis  = (int)(((uintptr_t)rowp >> 2) & 3);
    int head = (4 - mis) & 3;
    if (head > ncols) head = ncols;
    if (tid < head) insert(rowp[tid], tid);

    const int nvec4 = (ncols - head) >> 2;
    const f32x4* __restrict__ vp = (const f32x4*)(rowp + head);

    int j = tid;

    // Warmup: ungated (T not yet meaningful).
    for (int w = 0; w < WARM; ++w, j += NT) {
        if (j < nvec4) {
            f32x4 f = vp[j];
            const int b = head + 4 * j;
            insert(f[0], b); insert(f[1], b + 1); insert(f[2], b + 2); insert(f[3], b + 3);
        }
    }

    float T = refresh(-FLT_MAX);

    // Chunk 2: gated, single float4 per iteration.
    for (int w = 0; w < CH2; ++w, j += NT) {
        if (j < nvec4) {
            f32x4 f = vp[j];
            const float m = fmaxf(fmaxf(f[0], f[1]), fmaxf(f[2], f[3]));
            if (m >= T) {
                const int b = head + 4 * j;
                if (f[0] >= T) insert(f[0], b);
                if (f[1] >= T) insert(f[1], b + 1);
                if (f[2] >= T) insert(f[2], b + 2);
                if (f[3] >= T) insert(f[3], b + 3);
            }
        }
    }

    T = refresh(T);

    // Chunk 3: gated, 4 nontemporal float4 loads issued back-to-back
    // (4 KB/wave in flight) before any use — MLP + amortized loop overhead.
    for (; j + 3 * NT < nvec4; j += 4 * NT) {
        f32x4 f0 = __builtin_nontemporal_load(vp + j);
        f32x4 f1 = __builtin_nontemporal_load(vp + j + NT);
        f32x4 f2 = __builtin_nontemporal_load(vp + j + 2 * NT);
        f32x4 f3 = __builtin_nontemporal_load(vp + j + 3 * NT);
        const float m0 = fmaxf(fmaxf(f0[0], f0[1]), fmaxf(f0[2], f0[3]));
        const float m1 = fmaxf(fmaxf(f1[0], f1[1]), fmaxf(f1[2], f1[3]));
        const float m2 = fmaxf(fmaxf(f2[0], f2[1]), fmaxf(f2[2], f2[3]));
        const float m3 = fmaxf(fmaxf(f3[0], f3[1]), fmaxf(f3[2], f3[3]));
        const float mm = fmaxf(fmaxf(m0, m1), fmaxf(m2, m3));
        if (mm >= T) {
            if (m0 >= T) {
                const int b = head + 4 * j;
                if (f0[0] >= T) insert(f0[0], b);
                if (f0[1] >= T) insert(f0[1], b + 1);
                if (f0[2] >= T) insert(f0[2], b + 2);
                if (f0[3] >= T) insert(f0[3], b + 3);
            }
            if (m1 >= T) {
                const int b = head + 4 * (j + NT);
                if (f1[0] >= T) insert(f1[0], b);
                if (f1[1] >= T) insert(f1[1], b + 1);
                if (f1[2] >= T) insert(f1[2], b + 2);
                if (f1[3] >= T) insert(f1[3], b + 3);
            }
            if (m2 >= T) {
                const int b = head + 4 * (j + 2 * NT);
                if (f2[0] >= T) insert(f2[0], b);
                if (f2[1] >= T) insert(f2[1], b + 1);
                if (f2[2] >= T) insert(f2[2], b + 2);
                if (f2[3] >= T) insert(f2[3], b + 3);
            }
            if (m3 >= T) {
                const int b = head + 4 * (j + 3 * NT);
                if (f3[0] >= T) insert(f3[0], b);
                if (f3[1] >= T) insert(f3[1], b + 1);
                if (f3[2] >= T) insert(f3[2], b + 2);
                if (f3[3] >= T) insert(f3[3], b + 3);
            }
        }
    }
    // Remainder float4s.
    for (; j < nvec4; j += NT) {
        f32x4 f = vp[j];
        const float m = fmaxf(fmaxf(f[0], f[1]), fmaxf(f[2], f[3]));
        if (m >= T) {
            const int b = head + 4 * j;
            if (f[0] >= T) insert(f[0], b);
            if (f[1] >= T) insert(f[1], b + 1);
            if (f[2] >= T) insert(f[2], b + 2);
            if (f[3] >= T) insert(f[3], b + 3);
        }
    }

    // Scalar tail.
    const int tb = head + 4 * nvec4;
    for (int c = tb + tid; c < ncols; c += NT) insert(rowp[c], c);

    // Final block-wide top-8 extraction (tie-break: smaller index wins).
    for (int r = 0; r < K; ++r) {
        float bv = v[0];
        int   bi = id[0];
        int   bt = tid;
#pragma unroll
        for (int off = 32; off >= 1; off >>= 1) {
            float ov = __shfl_xor(bv, off);
            int   oi = __shfl_xor(bi, off);
            int   ot = __shfl_xor(bt, off);
            if (ov > bv || (ov == bv && oi < bi)) { bv = ov; bi = oi; bt = ot; }
        }
        if (lane == 0) { sv[wave] = bv; si[wave] = bi; st[wave] = bt; }
        __syncthreads();

        float wv = sv[0]; int wi = si[0]; int wt = st[0];
#pragma unroll
        for (int w = 1; w < NW; ++w) {
            if (sv[w] > wv || (sv[w] == wv && si[w] < wi)) {
                wv = sv[w]; wi = si[w]; wt = st[w];
            }
        }

        if (tid == wt) {
#pragma unroll
            for (int p = 0; p < K - 1; ++p) { v[p] = v[p + 1]; id[p] = id[p + 1]; }
            v[K - 1] = -FLT_MAX; id[K - 1] = 0x7fffffff;
        }
        if (tid == 0) { rv[r] = wv; ri[r] = wi; }
        __syncthreads();
    }

    if (tid < K) {
        out[(size_t)row * K + tid]                     = rv[tid];
        out[(size_t)nrows * K + (size_t)row * K + tid] = (float)ri[tid];
    }
}

extern "C" void kernel_launch(void* const* d_in, const int* in_sizes, int n_in,
                              void* d_out, int out_size, void* d_ws, size_t ws_size,
                              hipStream_t stream) {
    const float* x = (const float*)d_in[0];
    float* out = (float*)d_out;
    const int nrows = 4096;
    const int ncols = in_sizes[0] / nrows;   // 50257
    topk8_kernel<<<nrows, NT, 0, stream>>>(x, out, ncols, nrows);
}